// Round 8
// baseline (298.792 us; speedup 1.0000x reference)
//
#include <hip/hip_runtime.h>
#include <hip/hip_bf16.h>

#define B_  8
#define LQ  160
#define LK  160

// ---------------------------------------------------------------------------
// Multi-op fp32 GEMM, full K, no atomics, software-pipelined global loads.
// C[m,n] = sum_k A[m,k]*W[n,k] + bias[n]; A [1280,512] lda=512, W [N,K], C ld 512.
// ---------------------------------------------------------------------------
struct GOps {
    const float* A[3];
    const float* W[3];
    const float* Bi[3];
    float*       C[3];
};

__global__ __launch_bounds__(256) void gemm_f(GOps ops, int K)
{
    const int op = blockIdx.z;
    const float* __restrict__ A  = ops.A[op];
    const float* __restrict__ W  = ops.W[op];
    const float* __restrict__ Bi = ops.Bi[op];
    float* __restrict__       C  = ops.C[op];

    const int m0 = blockIdx.y << 6;
    const int n0 = blockIdx.x << 6;
    const int tid = threadIdx.x;
    const int tm  = tid >> 4;
    const int tn  = tid & 15;
    const int lr  = tid >> 2;
    const int lk4 = (tid & 3) << 2;

    __shared__ float As[16][64];
    __shared__ float Ws[16][64];

    float acc[4][4];
#pragma unroll
    for (int i = 0; i < 4; i++)
#pragma unroll
        for (int j = 0; j < 4; j++) acc[i][j] = 0.f;

    const float* Arow = A + (long)(m0 + lr) * 512 + lk4;
    const float* Wrow = W + (long)(n0 + lr) * K + lk4;
    float4 av = *(const float4*)(Arow);
    float4 wv = *(const float4*)(Wrow);

    for (int k0 = 0; k0 < K; k0 += 16) {
        __syncthreads();
        As[lk4 + 0][lr] = av.x; As[lk4 + 1][lr] = av.y;
        As[lk4 + 2][lr] = av.z; As[lk4 + 3][lr] = av.w;
        Ws[lk4 + 0][lr] = wv.x; Ws[lk4 + 1][lr] = wv.y;
        Ws[lk4 + 2][lr] = wv.z; Ws[lk4 + 3][lr] = wv.w;
        __syncthreads();
        if (k0 + 16 < K) {
            av = *(const float4*)(Arow + k0 + 16);
            wv = *(const float4*)(Wrow + k0 + 16);
        }
#pragma unroll
        for (int kk = 0; kk < 16; kk++) {
            const float4 a4 = *(const float4*)(&As[kk][tm << 2]);
            const float4 b4 = *(const float4*)(&Ws[kk][tn << 2]);
            const float aa[4] = {a4.x, a4.y, a4.z, a4.w};
            const float bb[4] = {b4.x, b4.y, b4.z, b4.w};
#pragma unroll
            for (int i = 0; i < 4; i++)
#pragma unroll
                for (int j = 0; j < 4; j++)
                    acc[i][j] = fmaf(aa[i], bb[j], acc[i][j]);
        }
    }

    const float4 bv = *(const float4*)(Bi + n0 + (tn << 2));
    const float bArr[4] = {bv.x, bv.y, bv.z, bv.w};

#pragma unroll
    for (int i = 0; i < 4; i++) {
        float4 vo;
        vo.x = acc[i][0] + bArr[0]; vo.y = acc[i][1] + bArr[1];
        vo.z = acc[i][2] + bArr[2]; vo.w = acc[i][3] + bArr[3];
        *(float4*)(C + (long)(m0 + (tm << 2) + i) * 512 + n0 + (tn << 2)) = vo;
    }
}

// ---------------------------------------------------------------------------
// Fused per-chunk merge projections (K=64 GEMMs). z<8 -> y0 chunk z, else y1.
// BOTH paths use remapped columns: block covers s in [s0,s0+8) x r in [0,8),
// logical col ln -> weight row t = (ln&7)*64 + s0 + (ln>>3).
// y0: LDS-transposed to [s8][k8][r], written as contiguous 512-float runs/s
//     into y0t[b][c][s][k][r].
// y1: LDS-transposed to [m8][s8*8+r], written as contiguous 64-float runs/m
//     into y1p[m][c][s][r]  (c*512 + s*8 + r) -- r innermost for score s_load.
// ---------------------------------------------------------------------------
__global__ __launch_bounds__(256) void y_proj(
    const float* __restrict__ x0, const float* __restrict__ wm0, const float* __restrict__ bm0,
    const float* __restrict__ x1, const float* __restrict__ wm1, const float* __restrict__ bm1,
    float* __restrict__ y0t, float* __restrict__ y1p)
{
    const int z   = blockIdx.z;
    const bool is1 = z >= 8;
    const int c   = is1 ? z - 8 : z;
    const float* A  = (is1 ? x1 : x0) + (c << 6);      // column slice, lda=512
    const float* W  = (is1 ? wm1 : wm0) + c * 32768;   // [512][64]
    const float* Bi = (is1 ? bm1 : bm0) + (c << 9);

    const int m0 = blockIdx.y << 6;
    const int s0 = blockIdx.x << 3;
    const int tid = threadIdx.x;
    const int tm  = tid >> 4;
    const int tn  = tid & 15;
    const int lr  = tid >> 2;
    const int lk4 = (tid & 3) << 2;

    __shared__ float As[16][64];
    __shared__ float Ws[16][64];
    __shared__ float outT[4096];

    float acc[4][4];
#pragma unroll
    for (int i = 0; i < 4; i++)
#pragma unroll
        for (int j = 0; j < 4; j++) acc[i][j] = 0.f;

    const int wrow = ((lr & 7) << 6) + s0 + (lr >> 3);
    const float* Arow = A + (long)(m0 + lr) * 512 + lk4;
    const float* Wrow = W + (long)wrow * 64 + lk4;
    float4 av = *(const float4*)(Arow);
    float4 wv = *(const float4*)(Wrow);

    for (int k0 = 0; k0 < 64; k0 += 16) {
        __syncthreads();
        As[lk4 + 0][lr] = av.x; As[lk4 + 1][lr] = av.y;
        As[lk4 + 2][lr] = av.z; As[lk4 + 3][lr] = av.w;
        Ws[lk4 + 0][lr] = wv.x; Ws[lk4 + 1][lr] = wv.y;
        Ws[lk4 + 2][lr] = wv.z; Ws[lk4 + 3][lr] = wv.w;
        __syncthreads();
        if (k0 + 16 < 64) {
            av = *(const float4*)(Arow + k0 + 16);
            wv = *(const float4*)(Wrow + k0 + 16);
        }
#pragma unroll
        for (int kk = 0; kk < 16; kk++) {
            const float4 a4 = *(const float4*)(&As[kk][tm << 2]);
            const float4 b4 = *(const float4*)(&Ws[kk][tn << 2]);
            const float aa[4] = {a4.x, a4.y, a4.z, a4.w};
            const float bb[4] = {b4.x, b4.y, b4.z, b4.w};
#pragma unroll
            for (int i = 0; i < 4; i++)
#pragma unroll
                for (int j = 0; j < 4; j++)
                    acc[i][j] = fmaf(aa[i], bb[j], acc[i][j]);
        }
    }

    // bias for logical column ln = tn*4+j: t = (ln&7)*64 + s0 + (ln>>3)
    float bArr[4];
#pragma unroll
    for (int j = 0; j < 4; j++) {
        const int ln = (tn << 2) + j;
        bArr[j] = Bi[((ln & 7) << 6) + s0 + (ln >> 3)];
    }
    __syncthreads();
    if (is1) {
        // stage [m8][s8*8 + r]
#pragma unroll
        for (int i = 0; i < 4; i++) {
            const int m8 = (tm << 2) + i;
#pragma unroll
            for (int j = 0; j < 4; j++) {
                const int ln = (tn << 2) + j;
                outT[(m8 << 6) + ((ln >> 3) << 3) + (ln & 7)] = acc[i][j] + bArr[j];
            }
        }
        __syncthreads();
        // write: 64 rows x 64 contiguous floats at y1p[m][c*512 + s0*8]
#pragma unroll
        for (int p = 0; p < 4; p++) {
            const int idx = tid + (p << 8);     // float4 id 0..1023
            const int m8  = idx >> 4;
            const int f4  = idx & 15;
            *(float4*)(y1p + (long)(m0 + m8) * 4096 + (c << 9) + (s0 << 3) + (f4 << 2))
                = *(const float4*)&outT[idx << 2];
        }
    } else {
        // stage [s8][k8][r]
#pragma unroll
        for (int i = 0; i < 4; i++) {
            const int k8 = (tm << 2) + i;
#pragma unroll
            for (int j = 0; j < 4; j++) {
                const int ln = (tn << 2) + j;
                outT[((ln >> 3) << 9) + (k8 << 3) + (ln & 7)] = acc[i][j] + bArr[j];
            }
        }
        __syncthreads();
        // write 8 runs of 512 contiguous floats (one per s8)
#pragma unroll
        for (int p = 0; p < 4; p++) {
            const int s8  = (p << 1) + (tid >> 7);
            const int u4  = tid & 127;
            const int k8  = u4 >> 1;
            const int r   = (u4 & 1) << 2;
            const int m   = m0 + k8;
            const int bidx = m / 160;
            const int kmod = m - bidx * 160;
            const int s   = s0 + s8;
            float4* dst = (float4*)(y0t +
                (((long)(bidx * 8 + c) * 64 + s) * 160 + kmod) * 8 + r);
            *dst = *(const float4*)&outT[(s8 << 9) + (u4 << 2)];
        }
    }
}

// ---------------------------------------------------------------------------
// Per-(b, 4-q-tile, c) partial scores, NO LDS: y1 and w_bo are wave-uniform ->
// read through uniform pointers (scalar s_load path, SGPR operands in the FMAs).
// No divergent early-return (keeps loads scalarizable); OOB lanes clamp k.
// y0: per-lane 2x float4 per s, prefetched one s ahead.
// scores_p: [B][LQ][C][LK]
// ---------------------------------------------------------------------------
__global__ __launch_bounds__(192) void score_partial(
    const float* __restrict__ y1p, const float* __restrict__ y0t,
    const float* __restrict__ wbo, float* __restrict__ scores_p)
{
    const int id = blockIdx.x;
    const int c  = id & 7;
    const int j  = id >> 3;
    const int b  = j / 40;
    const int q0 = (j - b * 40) << 2;
    const int k  = threadIdx.x;
    const int kc = k < LK ? k : (LK - 1);     // clamp redundant lanes

    const float* wb = wbo + (c << 6);
    const float* y1r0 = y1p + (long)(b * LQ + q0) * 4096 + (c << 9);
    const float* y1r1 = y1r0 + 4096;
    const float* y1r2 = y1r0 + 8192;
    const float* y1r3 = y1r0 + 12288;
    const float* ybc = y0t + (((long)(b * 8 + c) * 64) * 160 + kc) * 8;

    float num[4] = {0.f, 0.f, 0.f, 0.f};
    float den[4] = {0.f, 0.f, 0.f, 0.f};

    float4 a0 = *(const float4*)(ybc);
    float4 a1 = *(const float4*)(ybc + 4);
#pragma unroll 2
    for (int s = 0; s < 64; s++) {
        const float a[8] = {a0.x, a0.y, a0.z, a0.w, a1.x, a1.y, a1.z, a1.w};
        const int sn = (s + 1) & 63;          // last iter reloads s=0 (harmless)
        a0 = *(const float4*)(ybc + (long)sn * 1280);
        a1 = *(const float4*)(ybc + (long)sn * 1280 + 4);
        const float w = wb[s];
        const int o = s << 3;
        {
            float zv = a[0] * y1r0[o];
            zv = fmaf(a[1], y1r0[o+1], zv); zv = fmaf(a[2], y1r0[o+2], zv);
            zv = fmaf(a[3], y1r0[o+3], zv); zv = fmaf(a[4], y1r0[o+4], zv);
            zv = fmaf(a[5], y1r0[o+5], zv); zv = fmaf(a[6], y1r0[o+6], zv);
            zv = fmaf(a[7], y1r0[o+7], zv);
            const float az = fabsf(zv);
            num[0] = fmaf(copysignf(__builtin_amdgcn_sqrtf(az), zv), w, num[0]);
            den[0] += az;
        }
        {
            float zv = a[0] * y1r1[o];
            zv = fmaf(a[1], y1r1[o+1], zv); zv = fmaf(a[2], y1r1[o+2], zv);
            zv = fmaf(a[3], y1r1[o+3], zv); zv = fmaf(a[4], y1r1[o+4], zv);
            zv = fmaf(a[5], y1r1[o+5], zv); zv = fmaf(a[6], y1r1[o+6], zv);
            zv = fmaf(a[7], y1r1[o+7], zv);
            const float az = fabsf(zv);
            num[1] = fmaf(copysignf(__builtin_amdgcn_sqrtf(az), zv), w, num[1]);
            den[1] += az;
        }
        {
            float zv = a[0] * y1r2[o];
            zv = fmaf(a[1], y1r2[o+1], zv); zv = fmaf(a[2], y1r2[o+2], zv);
            zv = fmaf(a[3], y1r2[o+3], zv); zv = fmaf(a[4], y1r2[o+4], zv);
            zv = fmaf(a[5], y1r2[o+5], zv); zv = fmaf(a[6], y1r2[o+6], zv);
            zv = fmaf(a[7], y1r2[o+7], zv);
            const float az = fabsf(zv);
            num[2] = fmaf(copysignf(__builtin_amdgcn_sqrtf(az), zv), w, num[2]);
            den[2] += az;
        }
        {
            float zv = a[0] * y1r3[o];
            zv = fmaf(a[1], y1r3[o+1], zv); zv = fmaf(a[2], y1r3[o+2], zv);
            zv = fmaf(a[3], y1r3[o+3], zv); zv = fmaf(a[4], y1r3[o+4], zv);
            zv = fmaf(a[5], y1r3[o+5], zv); zv = fmaf(a[6], y1r3[o+6], zv);
            zv = fmaf(a[7], y1r3[o+7], zv);
            const float az = fabsf(zv);
            num[3] = fmaf(copysignf(__builtin_amdgcn_sqrtf(az), zv), w, num[3]);
            den[3] += az;
        }
    }
    if (k < LK) {
#pragma unroll
        for (int q = 0; q < 4; q++)
            scores_p[(((long)(b * LQ + q0 + q)) * 8 + c) * 160 + k] =
                num[q] / fmaxf(__builtin_amdgcn_sqrtf(den[q]), 1e-12f);
    }
}

// ---------------------------------------------------------------------------
// Sum partials over c, softmax over k, att@vv, write attedT [B][512][LQ].
// b_bo dropped: softmax is shift-invariant.
// ---------------------------------------------------------------------------
__global__ __launch_bounds__(256) void softmax_attv(
    const float* __restrict__ scores_p, const float* __restrict__ vv,
    float* __restrict__ attedT)
{
    const int b  = blockIdx.y;
    const int q0 = blockIdx.x << 2;
    const int tid = threadIdx.x;

    __shared__ float scs[4][160];
    __shared__ float invd[4];

    for (int t = tid; t < 640; t += 256) {
        const int q = t / 160;
        const int k = t - q * 160;
        const float* sp = scores_p + ((long)(b * LQ + q0 + q)) * 1280 + k;
        float s = 0.f;
#pragma unroll
        for (int c = 0; c < 8; c++) s += sp[c * 160];
        scs[q][k] = s;
    }
    __syncthreads();

    const int w    = tid >> 6;
    const int lane = tid & 63;
    {
        const int q = w;
        float m = -1e30f;
        for (int kk = lane; kk < LK; kk += 64) m = fmaxf(m, scs[q][kk]);
#pragma unroll
        for (int off = 32; off; off >>= 1) m = fmaxf(m, __shfl_xor(m, off, 64));
        float sum = 0.f;
        for (int kk = lane; kk < LK; kk += 64) {
            const float e = __expf(scs[q][kk] - m);
            scs[q][kk] = e;
            sum += e;
        }
#pragma unroll
        for (int off = 32; off; off >>= 1) sum += __shfl_xor(sum, off, 64);
        if (lane == 0) invd[q] = 1.f / sum;
    }
    __syncthreads();

    float acc[2][4] = {{0.f,0.f,0.f,0.f},{0.f,0.f,0.f,0.f}};
    const float* vb = vv + (long)b * (LK * 512);
    for (int kk = 0; kk < LK; kk++) {
        const float* vr = vb + kk * 512;
        const float p0 = scs[0][kk], p1 = scs[1][kk];
        const float p2 = scs[2][kk], p3 = scs[3][kk];
        const float v0 = vr[tid], v1 = vr[tid + 256];
        acc[0][0] = fmaf(p0, v0, acc[0][0]); acc[0][1] = fmaf(p1, v0, acc[0][1]);
        acc[0][2] = fmaf(p2, v0, acc[0][2]); acc[0][3] = fmaf(p3, v0, acc[0][3]);
        acc[1][0] = fmaf(p0, v1, acc[1][0]); acc[1][1] = fmaf(p1, v1, acc[1][1]);
        acc[1][2] = fmaf(p2, v1, acc[1][2]); acc[1][3] = fmaf(p3, v1, acc[1][3]);
    }
#pragma unroll
    for (int j = 0; j < 2; j++) {
        const int h = tid + (j << 8);
#pragma unroll
        for (int q = 0; q < 4; q++)
            attedT[((long)b * 512 + h) * 160 + q0 + q] = acc[j][q] * invd[q];
    }
}

// ---------------------------------------------------------------------------
extern "C" void kernel_launch(void* const* d_in, const int* in_sizes, int n_in,
                              void* d_out, int out_size, void* d_ws, size_t ws_size,
                              hipStream_t stream) {
    const float* v    = (const float*)d_in[0];
    const float* kin  = (const float*)d_in[1];
    const float* q    = (const float*)d_in[2];
    const float* w_v  = (const float*)d_in[3];
    const float* b_v  = (const float*)d_in[4];
    const float* w_k  = (const float*)d_in[5];
    const float* b_k  = (const float*)d_in[6];
    const float* w_q  = (const float*)d_in[7];
    const float* b_q  = (const float*)d_in[8];
    const float* w0   = (const float*)d_in[9];
    const float* b0   = (const float*)d_in[10];
    const float* w1   = (const float*)d_in[11];
    const float* b1   = (const float*)d_in[12];
    const float* wm0  = (const float*)d_in[13];
    const float* bm0  = (const float*)d_in[14];
    const float* wm1  = (const float*)d_in[15];
    const float* bm1  = (const float*)d_in[16];
    const float* w_bo = (const float*)d_in[17];
    (void)d_in[18];  // b_bo unused: softmax is shift-invariant
    const float* w_m  = (const float*)d_in[19];
    const float* b_m  = (const float*)d_in[20];

    float* ws       = (float*)d_ws;
    float* vv       = ws;                  // 655360
    float* kk       = ws + 655360;         // 655360
    float* qq       = ws + 1310720;        // 655360
    float* x0       = ws + 1966080;        // 655360
    float* x1       = ws + 2621440;        // 655360
    float* y1p      = ws + 3276800;        // 5242880  [m][c][s][r]
    float* y0t      = ws + 8519680;        // 5242880  [B][c][s][k][r]
    float* attedT   = ws + 13762560;       // 655360   [B][512][LQ]
    float* scores_p = ws + 655360;         // 1638400, aliases kk/qq/x0 (dead by then)

    GOps oA;
    oA.A[0] = v;   oA.W[0] = w_v; oA.Bi[0] = b_v; oA.C[0] = vv;
    oA.A[1] = kin; oA.W[1] = w_k; oA.Bi[1] = b_k; oA.C[1] = kk;
    oA.A[2] = q;   oA.W[2] = w_q; oA.Bi[2] = b_q; oA.C[2] = qq;
    hipLaunchKernelGGL(gemm_f, dim3(8, 20, 3), dim3(256), 0, stream, oA, 512);

    GOps oB;
    oB.A[0] = kk; oB.W[0] = w0; oB.Bi[0] = b0; oB.C[0] = x0;
    oB.A[1] = qq; oB.W[1] = w1; oB.Bi[1] = b1; oB.C[1] = x1;
    oB.A[2] = nullptr; oB.W[2] = nullptr; oB.Bi[2] = nullptr; oB.C[2] = nullptr;
    hipLaunchKernelGGL(gemm_f, dim3(8, 20, 2), dim3(256), 0, stream, oB, 512);

    hipLaunchKernelGGL(y_proj, dim3(8, 20, 16), dim3(256), 0, stream,
                       x0, wm0, bm0, x1, wm1, bm1, y0t, y1p);

    hipLaunchKernelGGL(score_partial, dim3(2560), dim3(192), 0, stream,
                       y1p, y0t, w_bo, scores_p);

    hipLaunchKernelGGL(softmax_attv, dim3(40, 8), dim3(256), 0, stream,
                       scores_p, vv, attedT);

    GOps oF;
    oF.A[0] = attedT; oF.W[0] = w_m; oF.Bi[0] = b_m; oF.C[0] = (float*)d_out;
    oF.A[1] = nullptr; oF.W[1] = nullptr; oF.Bi[1] = nullptr; oF.C[1] = nullptr;
    oF.A[2] = nullptr; oF.W[2] = nullptr; oF.Bi[2] = nullptr; oF.C[2] = nullptr;
    hipLaunchKernelGGL(gemm_f, dim3(8, 20, 1), dim3(256), 0, stream, oF, 512);
}